// Round 5
// baseline (464.941 us; speedup 1.0000x reference)
//
#include <hip/hip_runtime.h>
#include <math.h>

typedef float f32x4 __attribute__((ext_vector_type(4)));
typedef unsigned short ushort8 __attribute__((ext_vector_type(8)));
typedef unsigned short ushort4v __attribute__((ext_vector_type(4)));
typedef __bf16 bf16x8 __attribute__((ext_vector_type(8)));
typedef unsigned int u32;

__device__ __forceinline__ unsigned short f2bf(float x) {
  union { float f; unsigned u; } v; v.f = x;
  unsigned r = v.u + 0x7FFFu + ((v.u >> 16) & 1u);   // RNE
  return (unsigned short)(r >> 16);
}
__device__ __forceinline__ float bf2f(unsigned short u) {
  union { unsigned u; float f; } c; c.u = ((unsigned)u) << 16; return c.f;
}

__device__ __forceinline__ f32x4 mfma16(ushort8 a, ushort8 b, f32x4 c) {
  return __builtin_amdgcn_mfma_f32_16x16x32_bf16(
      __builtin_bit_cast(bf16x8, a), __builtin_bit_cast(bf16x8, b), c, 0, 0, 0);
}

// async global->LDS, 16B per lane; LDS dest = wave-uniform base, HW adds lane*16
__device__ __forceinline__ void gload16(const void* g, void* l) {
  __builtin_amdgcn_global_load_lds((const __attribute__((address_space(1))) u32*)g,
                                   (__attribute__((address_space(3))) u32*)l, 16, 0, 0);
}

// ---------------------------------------------------------------------------
// bf16 GEMM: C[M,N] = A[M,K] @ Bt[N,K]^T + bias. 128x128, BK=64, 2-phase dbuf.
// flags: 1 = relu, 2 = bf16 output
// ---------------------------------------------------------------------------
__global__ __launch_bounds__(256) void gemm_bf16_kernel(
    const unsigned short* __restrict__ A, const unsigned short* __restrict__ Bt,
    const float* __restrict__ bias, void* __restrict__ C,
    int M, int N, int K, int flags)
{
  __shared__ __align__(16) char As0[128 * 128];
  __shared__ __align__(16) char Bs0[128 * 128];
  __shared__ __align__(16) char As1[128 * 128];
  __shared__ __align__(16) char Bs1[128 * 128];
  const int bn = blockIdx.x, bm = blockIdx.y;
  const int t = threadIdx.x;
  const int lane = t & 63, w = t >> 6, wm = w >> 1, wn = w & 1;
  const int l4 = lane & 15, lg = lane >> 4;
  const size_t K2 = (size_t)K * 2;

  f32x4 acc[4][4];
#pragma unroll
  for (int i = 0; i < 4; ++i)
#pragma unroll
    for (int j = 0; j < 4; ++j) acc[i][j] = f32x4{0.f, 0.f, 0.f, 0.f};

  const int lr = lane >> 3;
  const int ls = (lane & 7) ^ lr;
  const char* Ag = (const char*)A + (size_t)(bm * 128 + w * 32 + lr) * K2 + ls * 16;
  const char* Bg = (const char*)Bt + (size_t)(bn * 128 + w * 32 + lr) * K2 + ls * 16;
  const int wo = w * 4096;

  auto STAGE = [&](char* Al, char* Bl, int kt) {
    const size_t ko = (size_t)kt * 128;
#pragma unroll
    for (int i = 0; i < 4; ++i) {
      gload16(Ag + i * 8 * K2 + ko, Al + wo + i * 1024);
      gload16(Bg + i * 8 * K2 + ko, Bl + wo + i * 1024);
    }
  };
  auto COMPUTE = [&](const char* As, const char* Bs) {
#pragma unroll
    for (int ks = 0; ks < 2; ++ks) {
      const int kb = ks * 64 + lg * 16;
      ushort8 af[4], bfr[4];
#pragma unroll
      for (int mi = 0; mi < 4; ++mi) {
        int r = wm * 64 + mi * 16 + l4;
        af[mi] = *reinterpret_cast<const ushort8*>(As + r * 128 + (kb ^ ((r & 7) << 4)));
      }
#pragma unroll
      for (int ni = 0; ni < 4; ++ni) {
        int r = wn * 64 + ni * 16 + l4;
        bfr[ni] = *reinterpret_cast<const ushort8*>(Bs + r * 128 + (kb ^ ((r & 7) << 4)));
      }
#pragma unroll
      for (int mi = 0; mi < 4; ++mi)
#pragma unroll
        for (int ni = 0; ni < 4; ++ni)
          acc[mi][ni] = mfma16(af[mi], bfr[ni], acc[mi][ni]);
    }
  };

  const int nkt = K >> 6;   // even (16 or 64)
  STAGE(As0, Bs0, 0);
  __syncthreads();
  for (int kt = 0; kt < nkt; kt += 2) {
    STAGE(As1, Bs1, kt + 1);
    COMPUTE(As0, Bs0);
    __syncthreads();
    if (kt + 2 < nkt) STAGE(As0, Bs0, kt + 2);
    COMPUTE(As1, Bs1);
    __syncthreads();
  }

  const int relu = flags & 1, obf = flags & 2;
#pragma unroll
  for (int mi = 0; mi < 4; ++mi)
#pragma unroll
    for (int ni = 0; ni < 4; ++ni) {
      int col = bn * 128 + wn * 64 + ni * 16 + l4;
      float bia = bias[col];
#pragma unroll
      for (int j = 0; j < 4; ++j) {
        int row = bm * 128 + wm * 64 + mi * 16 + lg * 4 + j;
        float vv = acc[mi][ni][j] + bia;
        if (relu) vv = fmaxf(vv, 0.f);
        if (obf) ((unsigned short*)C)[(size_t)row * N + col] = f2bf(vv);
        else     ((float*)C)[(size_t)row * N + col] = vv;
      }
    }
}

// ---------------------------------------------------------------------------
// Flash attention, bf16, log2-domain softmax (Q pre-scaled by 0.125*log2e).
// Block = (qt, h, b): 64 q-rows, 4 waves x 16 q-rows.
// Pipelined: K/maskbias via global_load_lds (pre-swizzled src), V via regs
// (async split); raw s_barrier + vmcnt drain only at tile top.
// ---------------------------------------------------------------------------
constexpr int kS = 1024, kD = 1024, kDH = 64;

__global__ __launch_bounds__(256) void attn_kernel(
    const unsigned short* __restrict__ Qg, const unsigned short* __restrict__ Kg,
    const unsigned short* __restrict__ Vg, int qs, int ks_,
    const unsigned short* __restrict__ mbias, unsigned short* __restrict__ Og)
{
  __shared__ __align__(16) char Qs[8192];
  __shared__ __align__(16) char Ks0[8192];
  __shared__ __align__(16) char Ks1[8192];
  __shared__ __align__(16) char Ms0[8192];
  __shared__ __align__(16) char Ms1[8192];
  __shared__ __align__(16) char VT0[8192];
  __shared__ __align__(16) char VT1[8192];
  __shared__ __align__(16) char Ps[8192];
  const int qt = blockIdx.x, h = blockIdx.y, b = blockIdx.z;
  const int t = threadIdx.x, lane = t & 63, w = t >> 6;
  const int l4 = lane & 15, lg = lane >> 4;
  const int lr = lane >> 3, sg = (lane & 7) ^ lr;

  {  // stage Q once (per-wave rows; DS pipe in-order within wave)
    int r = t >> 2, c0 = (t & 3) * 16;
    const unsigned short* src = Qg + (size_t)(b * kS + qt * 64 + r) * qs + h * kDH + c0;
#pragma unroll
    for (int hf = 0; hf < 2; ++hf) {
      ushort8 v = *reinterpret_cast<const ushort8*>(src + hf * 8);
      int c = c0 + hf * 8;
      *reinterpret_cast<ushort8*>(Qs + r * 128 + ((c * 2) ^ ((r & 7) << 4))) = v;
    }
  }

  // K tile: LDS row r slot s holds cols (s^(r&7))*8..+7  (read: kb ^ ((r&7)<<4))
  auto stageK = [&](char* Kl, int kt) {
    const char* base = (const char*)(Kg + (size_t)(b * kS + kt * 64) * ks_ + h * kDH) + sg * 16;
    gload16(base + (size_t)(w * 16 + lr) * (ks_ * 2), Kl + w * 2048);
    gload16(base + (size_t)(w * 16 + 8 + lr) * (ks_ * 2), Kl + w * 2048 + 1024);
  };
  // maskbias: global already permuted per q-row; straight row-segment copy
  auto stageM = [&](char* Ml, int kt) {
    const char* base = (const char*)mbias + ((size_t)(b * 1024 + qt * 64) * 1024 + kt * 64) * 2
                       + (lane & 7) * 16;
    gload16(base + (size_t)(w * 16 + lr) * 2048, Ml + w * 2048);
    gload16(base + (size_t)(w * 16 + 8 + lr) * 2048, Ml + w * 2048 + 1024);
  };

  float m_r[4], l_r[4];
  f32x4 o[4];
#pragma unroll
  for (int j = 0; j < 4; ++j) { m_r[j] = -1e30f; l_r[j] = 0.f; }
#pragma unroll
  for (int di = 0; di < 4; ++di) o[di] = f32x4{0.f, 0.f, 0.f, 0.f};

  ushort8 vA0, vA1, vB0, vB1;
  stageK(Ks0, 0);
  stageM(Ms0, 0);
  {
    const unsigned short* vsrc = Vg + (size_t)(b * kS + (t >> 2)) * ks_ + h * kDH + (t & 3) * 16;
    vA0 = *reinterpret_cast<const ushort8*>(vsrc);
    vA1 = *reinterpret_cast<const ushort8*>(vsrc + 8);
  }

#define ATTN_TILE(KC, MC, VC, KN, MN, VC0, VC1, VN0, VN1, KTV)                           \
  {                                                                                      \
    asm volatile("s_waitcnt vmcnt(0)" ::: "memory");                                     \
    __builtin_amdgcn_s_barrier();                                                        \
    __builtin_amdgcn_sched_barrier(0);                                                   \
    { /* V-transpose write: conflict-free swizzle */                                     \
      int key2 = (t >> 2) * 2, c0 = (t & 3) * 16;                                        \
      _Pragma("unroll")                                                                  \
      for (int i = 0; i < 8; ++i) {                                                      \
        int dh = c0 + i;                                                                 \
        *(unsigned short*)(VC + dh * 128 +                                               \
            (key2 ^ ((dh & 7) << 4) ^ ((dh >> 4) << 5))) = VC0[i];                       \
      }                                                                                  \
      _Pragma("unroll")                                                                  \
      for (int i = 0; i < 8; ++i) {                                                      \
        int dh = c0 + 8 + i;                                                             \
        *(unsigned short*)(VC + dh * 128 +                                               \
            (key2 ^ ((dh & 7) << 4) ^ ((dh >> 4) << 5))) = VC1[i];                       \
      }                                                                                  \
    }                                                                                    \
    if ((KTV) + 1 < 16) { /* prefetch next tile (flies under compute) */                 \
      stageK(KN, (KTV) + 1);                                                             \
      stageM(MN, (KTV) + 1);                                                             \
      const unsigned short* vsrc = Vg +                                                  \
          (size_t)(b * kS + ((KTV) + 1) * 64 + (t >> 2)) * ks_ + h * kDH + (t & 3) * 16; \
      VN0 = *reinterpret_cast<const ushort8*>(vsrc);                                     \
      VN1 = *reinterpret_cast<const ushort8*>(vsrc + 8);                                 \
    }                                                                                    \
    f32x4 sc[4];                                                                         \
    _Pragma("unroll")                                                                    \
    for (int ni = 0; ni < 4; ++ni) sc[ni] = f32x4{0.f, 0.f, 0.f, 0.f};                   \
    __builtin_amdgcn_s_setprio(1);                                                       \
    _Pragma("unroll")                                                                    \
    for (int ks = 0; ks < 2; ++ks) {                                                     \
      const int kb = ks * 64 + lg * 16;                                                  \
      int qr = w * 16 + l4;                                                              \
      ushort8 a = *(const ushort8*)(Qs + qr * 128 + (kb ^ ((qr & 7) << 4)));             \
      _Pragma("unroll")                                                                  \
      for (int ni = 0; ni < 4; ++ni) {                                                   \
        int kr = ni * 16 + l4;                                                           \
        ushort8 bb = *(const ushort8*)(KC + kr * 128 + (kb ^ ((kr & 7) << 4)));          \
        sc[ni] = mfma16(a, bb, sc[ni]);                                                  \
      }                                                                                  \
    }                                                                                    \
    __builtin_amdgcn_s_setprio(0);                                                       \
    float pmax[4];                                                                       \
    _Pragma("unroll")                                                                    \
    for (int j = 0; j < 4; ++j) {                                                        \
      int row = lg * 4 + j;                                                              \
      _Pragma("unroll")                                                                  \
      for (int ni = 0; ni < 4; ++ni) {                                                   \
        int col = ni * 16 + l4;                                                          \
        unsigned short mu = *(const unsigned short*)(MC + w * 2048 + row * 128 +         \
            ((col * 2) ^ ((row & 7) << 4) ^ ((row & 8) << 2)));                          \
        sc[ni][j] += bf2f(mu);                                                           \
      }                                                                                  \
      pmax[j] = fmaxf(fmaxf(sc[0][j], sc[1][j]), fmaxf(sc[2][j], sc[3][j]));             \
    }                                                                                    \
    _Pragma("unroll")                                                                    \
    for (int j = 0; j < 4; ++j) {                                                        \
      pmax[j] = fmaxf(pmax[j], __shfl_xor(pmax[j], 1, 64));                              \
      pmax[j] = fmaxf(pmax[j], __shfl_xor(pmax[j], 2, 64));                              \
      pmax[j] = fmaxf(pmax[j], __shfl_xor(pmax[j], 4, 64));                              \
      pmax[j] = fmaxf(pmax[j], __shfl_xor(pmax[j], 8, 64));                              \
    }                                                                                    \
    bool need = (pmax[0] > m_r[0] + 8.f) || (pmax[1] > m_r[1] + 8.f) ||                  \
                (pmax[2] > m_r[2] + 8.f) || (pmax[3] > m_r[3] + 8.f);                    \
    if (__any(need)) {                                                                   \
      _Pragma("unroll")                                                                  \
      for (int j = 0; j < 4; ++j) {                                                      \
        float mn = fmaxf(m_r[j], pmax[j]);                                               \
        float al = exp2f(m_r[j] - mn);                                                   \
        m_r[j] = mn; l_r[j] *= al;                                                       \
        o[0][j] *= al; o[1][j] *= al; o[2][j] *= al; o[3][j] *= al;                      \
      }                                                                                  \
    }                                                                                    \
    float rsum[4] = {0.f, 0.f, 0.f, 0.f};                                                \
    _Pragma("unroll")                                                                    \
    for (int ni = 0; ni < 4; ++ni)                                                       \
      _Pragma("unroll")                                                                  \
      for (int j = 0; j < 4; ++j) {                                                      \
        float p = exp2f(sc[ni][j] - m_r[j]);                                             \
        sc[ni][j] = p;                                                                   \
        rsum[j] += p;                                                                    \
      }                                                                                  \
    _Pragma("unroll")                                                                    \
    for (int j = 0; j < 4; ++j) {                                                        \
      rsum[j] += __shfl_xor(rsum[j], 1, 64);                                             \
      rsum[j] += __shfl_xor(rsum[j], 2, 64);                                             \
      rsum[j] += __shfl_xor(rsum[j], 4, 64);                                             \
      rsum[j] += __shfl_xor(rsum[j], 8, 64);                                             \
      l_r[j] += rsum[j];                                                                 \
    }                                                                                    \
    { /* P -> per-wave LDS region, conflict-free swizzle */                              \
      char* Pw = Ps + w * 2048;                                                          \
      _Pragma("unroll")                                                                  \
      for (int ni = 0; ni < 4; ++ni)                                                     \
        _Pragma("unroll")                                                                \
        for (int j = 0; j < 4; ++j) {                                                    \
          int row = lg * 4 + j, col = ni * 16 + l4;                                      \
          *(unsigned short*)(Pw + row * 128 +                                            \
              ((col * 2) ^ ((row & 7) << 4) ^ ((row & 8) << 2))) =                       \
              __builtin_bit_cast(unsigned short, (__bf16)sc[ni][j]);                     \
        }                                                                                \
    }                                                                                    \
    asm volatile("s_waitcnt lgkmcnt(0)" ::: "memory");                                   \
    __builtin_amdgcn_s_barrier();                                                        \
    __builtin_amdgcn_sched_barrier(0);                                                   \
    __builtin_amdgcn_s_setprio(1);                                                       \
    {                                                                                    \
      const char* Pw = Ps + w * 2048;                                                    \
      _Pragma("unroll")                                                                  \
      for (int ks = 0; ks < 2; ++ks) {                                                   \
        const int kb = ks * 64 + lg * 16;                                                \
        ushort8 pa = *(const ushort8*)(Pw + l4 * 128 +                                   \
            (kb ^ ((l4 & 7) << 4) ^ ((l4 & 8) << 2)));                                   \
        _Pragma("unroll")                                                                \
        for (int di = 0; di < 4; ++di) {                                                 \
          int vr2 = di * 16 + l4;                                                        \
          ushort8 vb = *(const ushort8*)(VC + vr2 * 128 +                                \
              (kb ^ ((vr2 & 7) << 4) ^ ((vr2 >> 4) << 5)));                              \
          o[di] = mfma16(pa, vb, o[di]);                                                 \
        }                                                                                \
      }                                                                                  \
    }                                                                                    \
    __builtin_amdgcn_s_setprio(0);                                                       \
  }

  for (int kt = 0; kt < 16; kt += 2) {
    ATTN_TILE(Ks0, Ms0, VT0, Ks1, Ms1, vA0, vA1, vB0, vB1, kt);
    ATTN_TILE(Ks1, Ms1, VT1, Ks0, Ms0, vB0, vB1, vA0, vA1, kt + 1);
  }
#undef ATTN_TILE

  float rinv[4];
#pragma unroll
  for (int j = 0; j < 4; ++j) rinv[j] = 1.0f / l_r[j];
#pragma unroll
  for (int di = 0; di < 4; ++di) {
    int col = h * kDH + di * 16 + l4;
#pragma unroll
    for (int j = 0; j < 4; ++j) {
      int qrow = qt * 64 + w * 16 + lg * 4 + j;
      Og[(size_t)(b * kS + qrow) * kD + col] =
          __builtin_bit_cast(unsigned short, (__bf16)(o[di][j] * rinv[j]));
    }
  }
}

// ---------------------------------------------------------------------------
// out = LayerNorm(x + y) * g + be (D=1024); x f32, y bf16; f32 out + opt bf16
// ---------------------------------------------------------------------------
__global__ __launch_bounds__(256) void addln_kernel(
    const float* __restrict__ x, const unsigned short* __restrict__ y,
    const float* __restrict__ g, const float* __restrict__ be,
    float* __restrict__ out, unsigned short* __restrict__ ob)
{
  const int row = blockIdx.x, t = threadIdx.x;
  const size_t base = (size_t)row * 1024 + t * 4;
  float4 xv = *reinterpret_cast<const float4*>(x + base);
  ushort4v yv = *reinterpret_cast<const ushort4v*>(y + base);
  float v0 = xv.x + bf2f(yv[0]), v1 = xv.y + bf2f(yv[1]);
  float v2 = xv.z + bf2f(yv[2]), v3 = xv.w + bf2f(yv[3]);
  float s1 = v0 + v1 + v2 + v3;
  float s2 = v0 * v0 + v1 * v1 + v2 * v2 + v3 * v3;
#pragma unroll
  for (int off = 1; off < 64; off <<= 1) {
    s1 += __shfl_xor(s1, off, 64);
    s2 += __shfl_xor(s2, off, 64);
  }
  __shared__ float r1[4], r2[4];
  const int w = t >> 6, lane = t & 63;
  if (lane == 0) { r1[w] = s1; r2[w] = s2; }
  __syncthreads();
  s1 = r1[0] + r1[1] + r1[2] + r1[3];
  s2 = r2[0] + r2[1] + r2[2] + r2[3];
  const float mean = s1 * (1.0f / 1024.0f);
  const float var = s2 * (1.0f / 1024.0f) - mean * mean;
  const float rs = rsqrtf(var + 1e-5f);
  float4 gv = *reinterpret_cast<const float4*>(g + t * 4);
  float4 bv = *reinterpret_cast<const float4*>(be + t * 4);
  float4 ov;
  ov.x = (v0 - mean) * rs * gv.x + bv.x;
  ov.y = (v1 - mean) * rs * gv.y + bv.y;
  ov.z = (v2 - mean) * rs * gv.z + bv.z;
  ov.w = (v3 - mean) * rs * gv.w + bv.w;
  *reinterpret_cast<float4*>(out + base) = ov;
  if (ob) {
    ushort4v bo;
    bo[0] = f2bf(ov.x); bo[1] = f2bf(ov.y); bo[2] = f2bf(ov.z); bo[3] = f2bf(ov.w);
    *reinterpret_cast<ushort4v*>(ob + base) = bo;
  }
}

// ---------------------------------------------------------------------------
__global__ __launch_bounds__(256) void cvt2_bf16_kernel(
    const float* __restrict__ a, const float* __restrict__ b,
    unsigned short* __restrict__ da, unsigned short* __restrict__ db, int n8each)
{
  int i = blockIdx.x * 256 + threadIdx.x;
  const float* s = a; unsigned short* d = da;
  if (i >= n8each) { s = b; d = db; i -= n8each; }
  if (i >= n8each) return;
  float4 f0 = reinterpret_cast<const float4*>(s)[i * 2];
  float4 f1 = reinterpret_cast<const float4*>(s)[i * 2 + 1];
  ushort8 v;
  v[0] = f2bf(f0.x); v[1] = f2bf(f0.y); v[2] = f2bf(f0.z); v[3] = f2bf(f0.w);
  v[4] = f2bf(f1.x); v[5] = f2bf(f1.y); v[6] = f2bf(f1.z); v[7] = f2bf(f1.w);
  reinterpret_cast<ushort8*>(d)[i] = v;
}

// W[K][N] f32 -> Wt[n][k] bf16 (dst stride = K)
__global__ __launch_bounds__(256) void transpose_cvt_kernel(
    const float* __restrict__ src, unsigned short* __restrict__ dst, int K, int N)
{
  __shared__ float tile[32][33];
  const int bx = blockIdx.x, by = blockIdx.y;
  const int tx = threadIdx.x & 31, ty = threadIdx.x >> 5;
#pragma unroll
  for (int i = 0; i < 4; ++i)
    tile[ty + i * 8][tx] = src[(size_t)(by * 32 + ty + i * 8) * N + bx * 32 + tx];
  __syncthreads();
#pragma unroll
  for (int i = 0; i < 4; ++i)
    dst[(size_t)(bx * 32 + ty + i * 8) * K + by * 32 + tx] = f2bf(tile[tx][ty + i * 8]);
}

// batched 1024x1024 transposes with per-entry scale, grid (32,32,8)
struct TPtrs { const float* s[8]; unsigned short* d[8]; float scale[8]; };
__global__ __launch_bounds__(256) void tcvt_batch_kernel(TPtrs p)
{
  __shared__ float tile[32][33];
  const float* __restrict__ src = p.s[blockIdx.z];
  unsigned short* __restrict__ dst = p.d[blockIdx.z];
  const float sc = p.scale[blockIdx.z];
  const int bx = blockIdx.x, by = blockIdx.y;
  const int tx = threadIdx.x & 31, ty = threadIdx.x >> 5;
#pragma unroll
  for (int i = 0; i < 4; ++i)
    tile[ty + i * 8][tx] = src[(size_t)(by * 32 + ty + i * 8) * 1024 + bx * 32 + tx];
  __syncthreads();
#pragma unroll
  for (int i = 0; i < 4; ++i)
    dst[(size_t)(bx * 32 + ty + i * 8) * 1024 + by * 32 + tx] = f2bf(tile[tx][ty + i * 8] * sc);
}

__global__ void biasprep_kernel(const float* sq, const float* sk, const float* sv,
                                const float* cq, const float* ck, const float* cv,
                                float* bsa, float* bca, float* bcq, float s)
{
  int i = blockIdx.x * 256 + threadIdx.x;
  if (i < 1024) { bsa[i] = sq[i] * s; bcq[i] = cq[i] * s; bca[i] = ck[i]; bca[i + 1024] = cv[i]; }
  else if (i < 2048) bsa[i] = sk[i - 1024];
  else if (i < 3072) bsa[i] = sv[i - 2048];
}

// mask int32 -> bf16 additive bias, pre-permuted per q-row for conflict-free
// LDS reads: within each 64-col tile, 16B-chunk slot holds src slot
// (slot ^ (q&7) ^ ((q&8)>>2)).
__global__ __launch_bounds__(256) void maskprep_kernel(
    const int* __restrict__ mask, unsigned short* __restrict__ mbias)
{
  int idx = blockIdx.x * 256 + threadIdx.x;   // 4*1024*128 = 524288 chunks
  int chunk = idx & 127;
  int q = (idx >> 7) & 1023;
  int b = idx >> 17;
  int tile = chunk >> 3, slot = chunk & 7;
  int sslot = slot ^ (q & 7) ^ ((q & 8) >> 2);
  const int* src = mask + ((size_t)(b * 1024 + q) * 1024) + tile * 64 + sslot * 8;
  int4 m0 = *reinterpret_cast<const int4*>(src);
  int4 m1 = *reinterpret_cast<const int4*>(src + 4);
  const unsigned short NEG = 0xCE6E;   // bf16 ~ -1e9
  ushort8 v;
  v[0] = m0.x ? 0 : NEG; v[1] = m0.y ? 0 : NEG; v[2] = m0.z ? 0 : NEG; v[3] = m0.w ? 0 : NEG;
  v[4] = m1.x ? 0 : NEG; v[5] = m1.y ? 0 : NEG; v[6] = m1.z ? 0 : NEG; v[7] = m1.w ? 0 : NEG;
  *reinterpret_cast<ushort8*>(mbias + (size_t)idx * 8) = v;
}

// ---------------------------------------------------------------------------
extern "C" void kernel_launch(void* const* d_in, const int* in_sizes, int n_in,
                              void* d_out, int out_size, void* d_ws, size_t ws_size,
                              hipStream_t stream)
{
  const float* tgt  = (const float*)d_in[0];
  const float* memi = (const float*)d_in[1];
  const int*   mask = (const int*)d_in[2];
  const float* sa_wq = (const float*)d_in[3];  const float* sa_bq = (const float*)d_in[4];
  const float* sa_wk = (const float*)d_in[5];  const float* sa_bk = (const float*)d_in[6];
  const float* sa_wv = (const float*)d_in[7];  const float* sa_bv = (const float*)d_in[8];
  const float* sa_wo = (const float*)d_in[9];  const float* sa_bo = (const float*)d_in[10];
  const float* ca_wq = (const float*)d_in[11]; const float* ca_bq = (const float*)d_in[12];
  const float* ca_wk = (const float*)d_in[13]; const float* ca_bk = (const float*)d_in[14];
  const float* ca_wv = (const float*)d_in[15]; const float* ca_bv = (const float*)d_in[16];
  const float* ca_wo = (const float*)d_in[17]; const float* ca_bo = (const float*)d_in[18];
  const float* w1 = (const float*)d_in[19]; const float* b1 = (const float*)d_in[20];
  const float* w2 = (const float*)d_in[21]; const float* b2 = (const float*)d_in[22];
  const float* g1 = (const float*)d_in[23]; const float* be1 = (const float*)d_in[24];
  const float* g2 = (const float*)d_in[25]; const float* be2 = (const float*)d_in[26];
  const float* g3 = (const float*)d_in[27]; const float* be3 = (const float*)d_in[28];
  float* out = (float*)d_out;
  char* W = (char*)d_ws;
  const size_t MB = 1 << 20;
  typedef unsigned short us;
  const float QSCALE = 0.18033688011112042f;   // 0.125 * log2(e)

  // workspace layout (byte offsets; total 114 MB)
  us* Wsaqkv = (us*)(W + 0);          // [3072][1024] bf16
  us* Wsao   = (us*)(W + 6 * MB);
  us* Wcaq   = (us*)(W + 8 * MB);
  us* Wcakv  = (us*)(W + 10 * MB);    // [2048][1024]
  us* Wcao   = (us*)(W + 14 * MB);
  us* W1t    = (us*)(W + 16 * MB);    // [4096][1024]
  us* W2t    = (us*)(W + 24 * MB);    // [1024][4096]
  float* b_saqkv = (float*)(W + 32 * MB);
  float* b_cakv  = (float*)(W + 32 * MB + 16384);
  float* b_caq   = (float*)(W + 32 * MB + 32768);
  us* tgt_bf = (us*)(W + 33 * MB);    // dead after SA-QKV gemm -> T2b
  us* T2b    = tgt_bf;
  us* mem_bf = (us*)(W + 41 * MB);
  us* QKV    = (us*)(W + 49 * MB);    // SA: [4096][3072]
  us* Qca    = (us*)(W + 49 * MB);
  us* KVca   = (us*)(W + 57 * MB);    // [4096][2048]
  us* T1b    = (us*)(W + 65 * MB);
  us* AO     = (us*)(W + 73 * MB);    // [4096][1024] bf16
  us* Hb     = (us*)(W + 49 * MB);    // FFN hidden [4096][4096] bf16 (49-81)
  us* Opb    = (us*)(W + 81 * MB);    // [4096][1024] bf16 proj outputs
  us* mbias  = (us*)(W + 89 * MB);    // [4][1024][1024] bf16, 8.4MB
  float* T1f = (float*)(W + 98 * MB); // 16MB; T2f aliases
  float* T2f = T1f;

  const int M = 4096;
  dim3 blk(256);
  auto gemm = [&](const us* Aa, const us* Bta, const float* bias, void* Cc,
                  int Nn, int Kk, int flags) {
    gemm_bf16_kernel<<<dim3(Nn / 128, M / 128), blk, 0, stream>>>(Aa, Bta, bias, Cc, M, Nn, Kk, flags);
  };

  // ---- prep ----
  TPtrs tp;
  tp.s[0] = sa_wq; tp.d[0] = Wsaqkv;              tp.scale[0] = QSCALE;
  tp.s[1] = sa_wk; tp.d[1] = Wsaqkv + 1024 * 1024; tp.scale[1] = 1.f;
  tp.s[2] = sa_wv; tp.d[2] = Wsaqkv + 2048 * 1024; tp.scale[2] = 1.f;
  tp.s[3] = sa_wo; tp.d[3] = Wsao;                 tp.scale[3] = 1.f;
  tp.s[4] = ca_wq; tp.d[4] = Wcaq;                 tp.scale[4] = QSCALE;
  tp.s[5] = ca_wk; tp.d[5] = Wcakv;                tp.scale[5] = 1.f;
  tp.s[6] = ca_wv; tp.d[6] = Wcakv + 1024 * 1024;  tp.scale[6] = 1.f;
  tp.s[7] = ca_wo; tp.d[7] = Wcao;                 tp.scale[7] = 1.f;
  tcvt_batch_kernel<<<dim3(32, 32, 8), blk, 0, stream>>>(tp);
  transpose_cvt_kernel<<<dim3(128, 32), blk, 0, stream>>>(w1, W1t, 1024, 4096);
  transpose_cvt_kernel<<<dim3(32, 128), blk, 0, stream>>>(w2, W2t, 4096, 1024);
  cvt2_bf16_kernel<<<dim3(4096), blk, 0, stream>>>(tgt, memi, tgt_bf, mem_bf, M * 1024 / 8);
  biasprep_kernel<<<dim3(12), blk, 0, stream>>>(sa_bq, sa_bk, sa_bv, ca_bq, ca_bk, ca_bv,
                                                b_saqkv, b_cakv, b_caq, QSCALE);
  maskprep_kernel<<<dim3(2048), blk, 0, stream>>>(mask, mbias);

  // ---- self-attention ----
  gemm(tgt_bf, Wsaqkv, b_saqkv, QKV, 3072, 1024, 2);
  attn_kernel<<<dim3(16, 16, 4), blk, 0, stream>>>(QKV, QKV + 1024, QKV + 2048, 3072, 3072, mbias, AO);
  gemm(AO, Wsao, sa_bo, Opb, 1024, 1024, 2);
  addln_kernel<<<dim3(M), blk, 0, stream>>>(tgt, Opb, g1, be1, T1f, T1b);

  // ---- cross-attention ----
  gemm(T1b, Wcaq, b_caq, Qca, 1024, 1024, 2);
  gemm(mem_bf, Wcakv, b_cakv, KVca, 2048, 1024, 2);
  attn_kernel<<<dim3(16, 16, 4), blk, 0, stream>>>(Qca, KVca, KVca + 1024, 1024, 2048, mbias, AO);
  gemm(AO, Wcao, ca_bo, Opb, 1024, 1024, 2);
  addln_kernel<<<dim3(M), blk, 0, stream>>>(T1f, Opb, g2, be2, T2f, T2b);

  // ---- FFN ----
  gemm(T2b, W1t, b1, Hb, 4096, 1024, 3);
  gemm(Hb, W2t, b2, Opb, 1024, 4096, 2);
  addln_kernel<<<dim3(M), blk, 0, stream>>>(T2f, Opb, g3, be3, out, nullptr);

  (void)in_sizes; (void)n_in; (void)out_size; (void)ws_size;
}